// Round 4
// baseline (111.714 us; speedup 1.0000x reference)
//
#include <hip/hip_runtime.h>
#include <hip/hip_bf16.h>
#include <cstdint>

#define BATCH 256
#define DIN   512
#define D2    128
#define NQ    16
#define NC    100
#define KFC   (D2 * D2)      // 16384

#define KS    64             // K-splits for FC
#define KCH   (KFC / KS)     // 256
#define STEPS (KCH / 32)     // 8 MFMA K-steps per block

#define ZPAD  132            // Zt/Et row stride (floats): 16B-aligned, low-conflict
#define CVT_BLKS 800         // k_prep: blocks doing fcw cvt (1638400 / (256*8))

typedef short short8 __attribute__((ext_vector_type(8)));
typedef float f32x4  __attribute__((ext_vector_type(4)));

// ---------------------------------------------------------------------------
// K1: fused prep.  blocks [0,800): fcw fp32->bf16.  blocks [800,1056):
// W2T[i][o] = 0.5*(W[2o][i]+W[2o+1][i]).
// ---------------------------------------------------------------------------
__global__ __launch_bounds__(256) void k_prep(const float* __restrict__ W,
                                              const float* __restrict__ fcw,
                                              float* __restrict__ W2T,
                                              __hip_bfloat16* __restrict__ fcw16) {
    int blk = blockIdx.x;
    if (blk < CVT_BLKS) {
        int i = (blk * 256 + threadIdx.x) * 8;
        float4 a = *(const float4*)(fcw + i);
        float4 b = *(const float4*)(fcw + i + 4);
        short8 v;
        __hip_bfloat16* h = (__hip_bfloat16*)&v;
        h[0] = __float2bfloat16(a.x); h[1] = __float2bfloat16(a.y);
        h[2] = __float2bfloat16(a.z); h[3] = __float2bfloat16(a.w);
        h[4] = __float2bfloat16(b.x); h[5] = __float2bfloat16(b.y);
        h[6] = __float2bfloat16(b.z); h[7] = __float2bfloat16(b.w);
        *(short8*)(fcw16 + i) = v;
    } else {
        int idx = (blk - CVT_BLKS) * 256 + threadIdx.x;   // 0..65535
        int o = idx & (D2 - 1);
        int i = idx >> 7;
        W2T[(size_t)i * D2 + o] =
            0.5f * (W[(size_t)(2 * o) * DIN + i] + W[(size_t)(2 * o + 1) * DIN + i]);
    }
}

// ---------------------------------------------------------------------------
// K2: fused per-batch pipeline, 1024 threads (16 waves -> 4 waves/SIMD).
// Z = W2 @ X_b; G = Z^T Z; G^{-1} (Gauss-Jordan, SPD); E = Z G^{-1};
// P2 = E Z^T -> bf16.  No intermediate HBM traffic.
// ---------------------------------------------------------------------------
__global__ __launch_bounds__(1024, 4) void k_zgep(const float* __restrict__ X,
                                                  const float* __restrict__ W2T,
                                                  __hip_bfloat16* __restrict__ P2) {
    __shared__ float Xs[DIN][NQ];     // 32 KB
    __shared__ float Zt[NQ][ZPAD];    // Zt[q][o]
    __shared__ float Et[NQ][ZPAD];    // Et[q][o]
    __shared__ float Gi[NQ][34];      // [G | I] -> [I | G^{-1}]

    int b = blockIdx.x;
    int t = threadIdx.x;

    // stage X_b: 8192 contiguous floats, 2 float4 per thread
    {
        const float4* src = (const float4*)(X + (size_t)b * DIN * NQ);
        float4* dst = (float4*)&Xs[0][0];
        dst[t]        = src[t];
        dst[t + 1024] = src[t + 1024];
    }
    __syncthreads();

    int o  = t & (D2 - 1);     // 0..127
    int q0 = (t >> 7) * 2;     // 0,2,..,14

    // phase Z: each thread -> (o, q0..q0+1)
    {
        const float* wp = W2T + o;
        float a0 = 0.f, a1 = 0.f;
        #pragma unroll 4
        for (int i = 0; i < DIN; ++i) {
            float w = wp[(size_t)i * D2];                 // coalesced, L2-hot
            float2 x = *(const float2*)&Xs[i][q0];        // wave-broadcast b64
            a0 = fmaf(w, x.x, a0);
            a1 = fmaf(w, x.y, a1);
        }
        Zt[q0][o]     = a0;
        Zt[q0 + 1][o] = a1;
    }
    __syncthreads();

    // phase G: threads 0..255 compute G = Z^T Z
    if (t < 256) {
        int qq = t >> 4, rr = t & 15;
        float s = 0.f;
        for (int i = 0; i < D2; i += 4) {
            float4 a = *(const float4*)&Zt[qq][i];
            float4 c = *(const float4*)&Zt[rr][i];
            s = fmaf(a.x, c.x, s); s = fmaf(a.y, c.y, s);
            s = fmaf(a.z, c.z, s); s = fmaf(a.w, c.w, s);
        }
        Gi[qq][rr] = s;
        Gi[qq][NQ + rr] = (qq == rr) ? 1.f : 0.f;
    }
    __syncthreads();

    // phase GJ: Gauss-Jordan on [G | I] (SPD -> no pivoting), threads 0..255.
    // ALL threads execute both barriers each iteration.
    {
        int r  = (t >> 4) & 15;
        int c0 = t & 15;
        int c1 = c0 + NQ;
        for (int k = 0; k < NQ; ++k) {
            float piv = 0.f, fac = 0.f, vk0 = 0.f, vk1 = 0.f;
            if (t < 256) {
                piv = Gi[k][k];  fac = Gi[r][k];
                vk0 = Gi[k][c0]; vk1 = Gi[k][c1];
            }
            __syncthreads();
            if (t < 256) {
                float inv = 1.f / piv;
                if (r == k) {
                    Gi[k][c0] = vk0 * inv;
                    Gi[k][c1] = vk1 * inv;
                } else {
                    float f = fac * inv;
                    Gi[r][c0] = fmaf(-f, vk0, Gi[r][c0]);
                    Gi[r][c1] = fmaf(-f, vk1, Gi[r][c1]);
                }
            }
            __syncthreads();
        }
    }

    // phase E: E = Z G^{-1}, stored q-major. Thread -> (o, q0..q0+1).
    {
        float a0 = 0.f, a1 = 0.f;
        #pragma unroll
        for (int rp = 0; rp < NQ; ++rp) {
            float z = Zt[rp][o];                           // contiguous b32
            a0 = fmaf(z, Gi[rp][NQ + q0], a0);             // broadcast
            a1 = fmaf(z, Gi[rp][NQ + q0 + 1], a1);
        }
        Et[q0][o]     = a0;
        Et[q0 + 1][o] = a1;
    }
    __syncthreads();

    // phase P2: P2 = E Z^T -> global bf16. Thread -> rows {ti, ti+64}, cols tj*8..+7
    {
        __hip_bfloat16* P2b = P2 + (size_t)b * KFC;
        int ti = t >> 4;          // 0..63
        int tj = t & 15;
        #pragma unroll
        for (int half = 0; half < 2; ++half) {
            int i = ti + half * 64;
            float acc[8] = {};
            #pragma unroll
            for (int r = 0; r < NQ; ++r) {
                float e  = Et[r][i];                           // 4-way broadcast
                float4 z0 = *(const float4*)&Zt[r][tj * 8];    // aligned b128
                float4 z1 = *(const float4*)&Zt[r][tj * 8 + 4];
                acc[0] = fmaf(e, z0.x, acc[0]); acc[1] = fmaf(e, z0.y, acc[1]);
                acc[2] = fmaf(e, z0.z, acc[2]); acc[3] = fmaf(e, z0.w, acc[3]);
                acc[4] = fmaf(e, z1.x, acc[4]); acc[5] = fmaf(e, z1.y, acc[5]);
                acc[6] = fmaf(e, z1.z, acc[6]); acc[7] = fmaf(e, z1.w, acc[7]);
            }
            short8 v;
            __hip_bfloat16* h = (__hip_bfloat16*)&v;
            #pragma unroll
            for (int j = 0; j < 8; ++j) h[j] = __float2bfloat16(acc[j]);
            *(short8*)(P2b + (size_t)i * D2 + tj * 8) = v;
        }
    }
}

// ---------------------------------------------------------------------------
// K3: MFMA split-K FC.  part[ks][b][c] = sum_{k in chunk} P2[b][k]*fcw[c][k]
// grid (16 bt, 64 ks) = 1024 blocks -> 4 blocks/CU.
// ---------------------------------------------------------------------------
__global__ __launch_bounds__(256) void k_fc(const __hip_bfloat16* __restrict__ P2,
                                            const __hip_bfloat16* __restrict__ fcw16,
                                            float* __restrict__ part) {
    int bt = blockIdx.x;            // 0..15
    int ks = blockIdx.y;            // 0..63
    int t  = threadIdx.x;
    int lane = t & 63;
    int w    = t >> 6;
    int m  = lane & 15;
    int kg = (lane >> 4) * 8;

    const __hip_bfloat16* pa =
        P2 + (size_t)(bt * 16 + m) * KFC + ks * KCH + kg;

    int c0 = w * 32 + m;
    int c1 = c0 + 16;
    bool v0 = (c0 < NC), v1 = (c1 < NC);
    const __hip_bfloat16* pb0 =
        fcw16 + (size_t)(v0 ? c0 : 0) * KFC + ks * KCH + kg;
    const __hip_bfloat16* pb1 =
        fcw16 + (size_t)(v1 ? c1 : 0) * KFC + ks * KCH + kg;

    f32x4 acc0 = {0.f, 0.f, 0.f, 0.f};
    f32x4 acc1 = {0.f, 0.f, 0.f, 0.f};
    short8 zz = {};

    #pragma unroll 4
    for (int s = 0; s < STEPS; ++s) {
        short8 a  = *(const short8*)(pa + s * 32);
        short8 b0 = v0 ? *(const short8*)(pb0 + s * 32) : zz;
        short8 b1 = v1 ? *(const short8*)(pb1 + s * 32) : zz;
        acc0 = __builtin_amdgcn_mfma_f32_16x16x32_bf16(a, b0, acc0, 0, 0, 0);
        acc1 = __builtin_amdgcn_mfma_f32_16x16x32_bf16(a, b1, acc1, 0, 0, 0);
    }

    int r0 = (lane >> 4) * 4;
    float* pp = part + ((size_t)ks * BATCH + bt * 16 + r0) * D2;
    #pragma unroll
    for (int j = 0; j < 4; ++j) {
        pp[(size_t)j * D2 + w * 32 + m]      = acc0[j];
        pp[(size_t)j * D2 + w * 32 + 16 + m] = acc1[j];
    }
}

// ---------------------------------------------------------------------------
// K4: out[b][c] = fcb[c] + sum_ks part[ks][b][c]
// ---------------------------------------------------------------------------
__global__ __launch_bounds__(128) void k_red(const float* __restrict__ part,
                                             const float* __restrict__ fcb,
                                             float* __restrict__ out) {
    int b = blockIdx.x;
    int c = threadIdx.x;
    if (c < NC) {
        float s = fcb[c];
        #pragma unroll 8
        for (int ks = 0; ks < KS; ++ks)
            s += part[((size_t)ks * BATCH + b) * D2 + c];
        out[(size_t)b * NC + c] = s;
    }
}

extern "C" void kernel_launch(void* const* d_in, const int* in_sizes, int n_in,
                              void* d_out, int out_size, void* d_ws, size_t ws_size,
                              hipStream_t stream) {
    const float* X   = (const float*)d_in[0];   // (256, 512, 16)
    const float* W   = (const float*)d_in[1];   // (256, 512)
    const float* fcw = (const float*)d_in[2];   // (100, 16384)
    const float* fcb = (const float*)d_in[3];   // (100,)
    float* out = (float*)d_out;                 // (256, 100)

    float* ws = (float*)d_ws;
    float*          W2T   = ws;                                   // 65536 f
    float*          part  = ws + 65536;                           // 64*256*128 = 2097152 f
    __hip_bfloat16* P2b16 = (__hip_bfloat16*)(ws + 65536 + 2097152);            // 4194304 bf16
    __hip_bfloat16* fcw16 = (__hip_bfloat16*)(ws + 65536 + 2097152 + 2097152);  // 1638400 bf16
    // total ws ~= 19.4 MB

    k_prep<<<dim3(CVT_BLKS + 256), 256, 0, stream>>>(W, fcw, W2T, fcw16);
    k_zgep<<<dim3(BATCH), 1024, 0, stream>>>(X, W2T, P2b16);
    k_fc  <<<dim3(16, KS), 256, 0, stream>>>(P2b16, fcw16, part);
    k_red <<<dim3(BATCH), 128, 0, stream>>>(part, fcb, out);
}

// Round 5
// 68.524 us; speedup vs baseline: 1.6303x; 1.6303x over previous
//
#include <hip/hip_runtime.h>
#include <hip/hip_bf16.h>
#include <cstdint>

#define BATCH 256
#define DIN   512
#define D2    128
#define NQ    16
#define NC    100
#define KFC   (D2 * D2)      // 16384

#define ZKS   4              // K-splits for Z GEMM (512/4 = 128 per split)
#define ZKL   (DIN / ZKS)    // 128

#define KS    64             // K-splits for FC
#define KCH   (KFC / KS)     // 256
#define STEPS (KCH / 32)     // 8 MFMA K-steps per block

#define ZPAD  132            // Zt/Et row stride (floats): 16B-aligned
#define CVT_BLKS 800         // k_prep: blocks doing fcw cvt (1638400 / (256*8))

typedef short short8 __attribute__((ext_vector_type(8)));
typedef float f32x4  __attribute__((ext_vector_type(4)));

// ---------------------------------------------------------------------------
// K1: fused prep.  blocks [0,800): fcw fp32->bf16.  blocks [800,1056):
// W2T[i][o] = 0.5*(W[2o][i]+W[2o+1][i]).
// ---------------------------------------------------------------------------
__global__ __launch_bounds__(256) void k_prep(const float* __restrict__ W,
                                              const float* __restrict__ fcw,
                                              float* __restrict__ W2T,
                                              __hip_bfloat16* __restrict__ fcw16) {
    int blk = blockIdx.x;
    if (blk < CVT_BLKS) {
        int i = (blk * 256 + threadIdx.x) * 8;
        float4 a = *(const float4*)(fcw + i);
        float4 b = *(const float4*)(fcw + i + 4);
        short8 v;
        __hip_bfloat16* h = (__hip_bfloat16*)&v;
        h[0] = __float2bfloat16(a.x); h[1] = __float2bfloat16(a.y);
        h[2] = __float2bfloat16(a.z); h[3] = __float2bfloat16(a.w);
        h[4] = __float2bfloat16(b.x); h[5] = __float2bfloat16(b.y);
        h[6] = __float2bfloat16(b.z); h[7] = __float2bfloat16(b.w);
        *(short8*)(fcw16 + i) = v;
    } else {
        int idx = (blk - CVT_BLKS) * 256 + threadIdx.x;   // 0..65535
        int o = idx & (D2 - 1);
        int i = idx >> 7;
        W2T[(size_t)i * D2 + o] =
            0.5f * (W[(size_t)(2 * o) * DIN + i] + W[(size_t)(2 * o + 1) * DIN + i]);
    }
}

// ---------------------------------------------------------------------------
// K2a: split-K GEMM for Z.  Zp[ks][b][q][o] = sum_{i in split} W2[o][i]*X[b][i][q]
// grid (BATCH, ZKS) = 1024 blocks -> 4 blocks/CU, W2T slices stay L2-hot.
// ---------------------------------------------------------------------------
__global__ __launch_bounds__(256) void k_z(const float* __restrict__ X,
                                           const float* __restrict__ W2T,
                                           float* __restrict__ Zp) {
    __shared__ float Xs[ZKL][NQ];   // 8 KB slice of X_b
    int b  = blockIdx.x;
    int ks = blockIdx.y;
    int t  = threadIdx.x;

    {
        const float4* src = (const float4*)(X + ((size_t)b * DIN + ks * ZKL) * NQ);
        float4* dst = (float4*)&Xs[0][0];
        for (int l = t; l < (ZKL * NQ) / 4; l += 256) dst[l] = src[l];
    }
    __syncthreads();

    int o  = t & (D2 - 1);
    int qh = (t >> 7) * 8;   // 0 or 8

    float acc[8] = {};
    #pragma unroll 4
    for (int i = 0; i < ZKL; ++i) {
        float w = W2T[(size_t)(ks * ZKL + i) * D2 + o];   // coalesced, L2-hot
        #pragma unroll
        for (int j = 0; j < 8; ++j) acc[j] = fmaf(w, Xs[i][qh + j], acc[j]);
    }

    float* zp = Zp + ((size_t)(ks * BATCH + b) * NQ) * D2;
    #pragma unroll
    for (int j = 0; j < 8; ++j)
        zp[(size_t)(qh + j) * D2 + o] = acc[j];          // coalesced per q
}

// ---------------------------------------------------------------------------
// K2b: per-batch epilogue, 512 threads (2 waves/SIMD).
// Z = sum Zp; G = Z^T Z; G^{-1} via SINGLE-WAVE register Gauss-Jordan
// (shuffles, zero barriers inside); E = Z G^{-1}; P2 = E Z^T -> bf16.
// Only 5 __syncthreads total.
// ---------------------------------------------------------------------------
__global__ __launch_bounds__(512) void k_gep(const float* __restrict__ Zp,
                                             __hip_bfloat16* __restrict__ P2) {
    __shared__ float Zt[NQ][ZPAD];    // Zt[q][o]
    __shared__ float Et[NQ][ZPAD];    // Et[q][o]
    __shared__ float Gi[NQ][36];      // [G | I] -> right half becomes G^{-1}

    int b = blockIdx.x;
    int t = threadIdx.x;

    // phase 1: reduce the ZKS partials (2048 floats = 512 float4, 1/thread)
    {
        const size_t s4 = (size_t)BATCH * NQ * D2 / 4;   // float4 per split
        const float4* zp = (const float4*)(Zp + ((size_t)b * NQ) * D2);
        float4 a0 = zp[t];
        float4 a1 = zp[t + s4];
        float4 a2 = zp[t + 2 * s4];
        float4 a3 = zp[t + 3 * s4];
        float4 s;
        s.x = (a0.x + a1.x) + (a2.x + a3.x);
        s.y = (a0.y + a1.y) + (a2.y + a3.y);
        s.z = (a0.z + a1.z) + (a2.z + a3.z);
        s.w = (a0.w + a1.w) + (a2.w + a3.w);
        int idx = t * 4;
        *(float4*)&Zt[idx >> 7][idx & (D2 - 1)] = s;
    }
    __syncthreads();

    // phase G: threads 0..255 compute G = Z^T Z, set up [G | I]
    if (t < 256) {
        int qq = t >> 4, rr = t & 15;
        float s = 0.f;
        for (int i = 0; i < D2; i += 4) {
            float4 a = *(const float4*)&Zt[qq][i];
            float4 c = *(const float4*)&Zt[rr][i];
            s = fmaf(a.x, c.x, s); s = fmaf(a.y, c.y, s);
            s = fmaf(a.z, c.z, s); s = fmaf(a.w, c.w, s);
        }
        Gi[qq][rr] = s;
        Gi[qq][NQ + rr] = (qq == rr) ? 1.f : 0.f;
    }
    __syncthreads();

    // phase GJ: wave 0 only, all in registers + shuffles. Lane l owns
    // row r = l&15, cols cg*8..cg*8+7 of the 16x32 [G|I] tableau.
    if (t < 64) {
        int r  = t & 15;
        int cg = t >> 4;
        float g[8];
        #pragma unroll
        for (int j = 0; j < 8; ++j) g[j] = Gi[r][cg * 8 + j];
        #pragma unroll
        for (int k = 0; k < NQ; ++k) {
            // pivot value G[k][k] and my row's multiplier G[r][k]
            float piv = __shfl(g[k & 7], (k >> 3) * 16 + k, 64);
            float fac = __shfl(g[k & 7], (k >> 3) * 16 + r, 64);
            float inv = 1.0f / piv;
            float f   = fac * inv;
            #pragma unroll
            for (int j = 0; j < 8; ++j) {
                float pv = __shfl(g[j], cg * 16 + k, 64);   // pivot row, my col
                g[j] = (r == k) ? pv * inv : fmaf(-f, pv, g[j]);
            }
        }
        if (cg >= 2) {   // write back G^{-1} (cols 16..31)
            #pragma unroll
            for (int j = 0; j < 8; ++j) Gi[r][cg * 8 + j] = g[j];
        }
    }
    __syncthreads();

    // phase E: E = Z G^{-1}, q-major. Thread -> (o, 4 q's).
    {
        int o  = t & (D2 - 1);
        int qg = (t >> 7) * 4;     // 0,4,8,12
        float acc[4] = {};
        #pragma unroll
        for (int rp = 0; rp < NQ; ++rp) {
            float z = Zt[rp][o];                       // contiguous b32
            #pragma unroll
            for (int j = 0; j < 4; ++j)
                acc[j] = fmaf(z, Gi[rp][NQ + qg + j], acc[j]);   // broadcast
        }
        #pragma unroll
        for (int j = 0; j < 4; ++j) Et[qg + j][o] = acc[j];
    }
    __syncthreads();

    // phase P2: P2 = E Z^T -> global bf16. Thread -> 4 rows, cols tj*8..+7
    {
        __hip_bfloat16* P2b = P2 + (size_t)b * KFC;
        int ti = t >> 4;          // 0..31
        int tj = t & 15;
        #pragma unroll
        for (int half = 0; half < 4; ++half) {
            int i = ti + half * 32;
            float acc[8] = {};
            #pragma unroll
            for (int r = 0; r < NQ; ++r) {
                float e   = Et[r][i];
                float4 z0 = *(const float4*)&Zt[r][tj * 8];
                float4 z1 = *(const float4*)&Zt[r][tj * 8 + 4];
                acc[0] = fmaf(e, z0.x, acc[0]); acc[1] = fmaf(e, z0.y, acc[1]);
                acc[2] = fmaf(e, z0.z, acc[2]); acc[3] = fmaf(e, z0.w, acc[3]);
                acc[4] = fmaf(e, z1.x, acc[4]); acc[5] = fmaf(e, z1.y, acc[5]);
                acc[6] = fmaf(e, z1.z, acc[6]); acc[7] = fmaf(e, z1.w, acc[7]);
            }
            short8 v;
            __hip_bfloat16* h = (__hip_bfloat16*)&v;
            #pragma unroll
            for (int j = 0; j < 8; ++j) h[j] = __float2bfloat16(acc[j]);
            *(short8*)(P2b + (size_t)i * D2 + tj * 8) = v;
        }
    }
}

// ---------------------------------------------------------------------------
// K3: MFMA split-K FC.  part[ks][b][c] = sum_{k in chunk} P2[b][k]*fcw[c][k]
// grid (16 bt, 64 ks) = 1024 blocks -> 4 blocks/CU.
// ---------------------------------------------------------------------------
__global__ __launch_bounds__(256) void k_fc(const __hip_bfloat16* __restrict__ P2,
                                            const __hip_bfloat16* __restrict__ fcw16,
                                            float* __restrict__ part) {
    int bt = blockIdx.x;            // 0..15
    int ks = blockIdx.y;            // 0..63
    int t  = threadIdx.x;
    int lane = t & 63;
    int w    = t >> 6;
    int m  = lane & 15;
    int kg = (lane >> 4) * 8;

    const __hip_bfloat16* pa =
        P2 + (size_t)(bt * 16 + m) * KFC + ks * KCH + kg;

    int c0 = w * 32 + m;
    int c1 = c0 + 16;
    bool v0 = (c0 < NC), v1 = (c1 < NC);
    const __hip_bfloat16* pb0 =
        fcw16 + (size_t)(v0 ? c0 : 0) * KFC + ks * KCH + kg;
    const __hip_bfloat16* pb1 =
        fcw16 + (size_t)(v1 ? c1 : 0) * KFC + ks * KCH + kg;

    f32x4 acc0 = {0.f, 0.f, 0.f, 0.f};
    f32x4 acc1 = {0.f, 0.f, 0.f, 0.f};
    short8 zz = {};

    #pragma unroll 4
    for (int s = 0; s < STEPS; ++s) {
        short8 a  = *(const short8*)(pa + s * 32);
        short8 b0 = v0 ? *(const short8*)(pb0 + s * 32) : zz;
        short8 b1 = v1 ? *(const short8*)(pb1 + s * 32) : zz;
        acc0 = __builtin_amdgcn_mfma_f32_16x16x32_bf16(a, b0, acc0, 0, 0, 0);
        acc1 = __builtin_amdgcn_mfma_f32_16x16x32_bf16(a, b1, acc1, 0, 0, 0);
    }

    int r0 = (lane >> 4) * 4;
    float* pp = part + ((size_t)ks * BATCH + bt * 16 + r0) * D2;
    #pragma unroll
    for (int j = 0; j < 4; ++j) {
        pp[(size_t)j * D2 + w * 32 + m]      = acc0[j];
        pp[(size_t)j * D2 + w * 32 + 16 + m] = acc1[j];
    }
}

// ---------------------------------------------------------------------------
// K4: out[b][c] = fcb[c] + sum_ks part[ks][b][c]
// ---------------------------------------------------------------------------
__global__ __launch_bounds__(128) void k_red(const float* __restrict__ part,
                                             const float* __restrict__ fcb,
                                             float* __restrict__ out) {
    int b = blockIdx.x;
    int c = threadIdx.x;
    if (c < NC) {
        float s = fcb[c];
        #pragma unroll 16
        for (int ks = 0; ks < KS; ++ks)
            s += part[((size_t)ks * BATCH + b) * D2 + c];
        out[(size_t)b * NC + c] = s;
    }
}

extern "C" void kernel_launch(void* const* d_in, const int* in_sizes, int n_in,
                              void* d_out, int out_size, void* d_ws, size_t ws_size,
                              hipStream_t stream) {
    const float* X   = (const float*)d_in[0];   // (256, 512, 16)
    const float* W   = (const float*)d_in[1];   // (256, 512)
    const float* fcw = (const float*)d_in[2];   // (100, 16384)
    const float* fcb = (const float*)d_in[3];   // (100,)
    float* out = (float*)d_out;                 // (256, 100)

    float* ws = (float*)d_ws;
    float*          W2T   = ws;                                   // 65536 f
    float*          Zp    = ws + 65536;                           // 2097152 f (8 MB)
    float*          part  = Zp;                                   // aliased: Zp dead after k_gep
    __hip_bfloat16* P2b16 = (__hip_bfloat16*)(ws + 65536 + 2097152);            // 4194304 bf16
    __hip_bfloat16* fcw16 = (__hip_bfloat16*)(ws + 65536 + 2097152 + 2097152);  // 1638400 bf16
    // total ws ~= 19.4 MB

    k_prep<<<dim3(CVT_BLKS + 256), 256, 0, stream>>>(W, fcw, W2T, fcw16);
    k_z   <<<dim3(BATCH, ZKS), 256, 0, stream>>>(X, W2T, Zp);
    k_gep <<<dim3(BATCH), 512, 0, stream>>>(Zp, P2b16);
    k_fc  <<<dim3(16, KS), 256, 0, stream>>>(P2b16, fcw16, part);
    k_red <<<dim3(BATCH), 128, 0, stream>>>(part, fcb, out);
}

// Round 6
// 65.299 us; speedup vs baseline: 1.7108x; 1.0494x over previous
//
#include <hip/hip_runtime.h>
#include <hip/hip_bf16.h>
#include <cstdint>

#define BATCH 256
#define DIN   512
#define D2    128
#define NQ    16
#define NC    100
#define KFC   (D2 * D2)      // 16384

#define ZKS   4              // K-splits for Z GEMM (512/4 = 128 per split)
#define ZKL   (DIN / ZKS)    // 128

#define KS    32             // K-splits for FC (round-3 measured config)
#define KCH   (KFC / KS)     // 512
#define STEPS (KCH / 32)     // 16 MFMA K-steps per block

#define ZPAD  132            // Zt/Et row stride (floats): 16B-aligned
#define CVT_BLKS 800         // k_prep: blocks doing fcw cvt (1638400 / (256*8))

typedef short short8 __attribute__((ext_vector_type(8)));
typedef float f32x4  __attribute__((ext_vector_type(4)));

// ---------------------------------------------------------------------------
// K1: fused prep.  blocks [0,800): fcw fp32->bf16.  blocks [800,1056):
// W2T[i][o] = 0.5*(W[2o][i]+W[2o+1][i]).
// ---------------------------------------------------------------------------
__global__ __launch_bounds__(256) void k_prep(const float* __restrict__ W,
                                              const float* __restrict__ fcw,
                                              float* __restrict__ W2T,
                                              __hip_bfloat16* __restrict__ fcw16) {
    int blk = blockIdx.x;
    if (blk < CVT_BLKS) {
        int i = (blk * 256 + threadIdx.x) * 8;
        float4 a = *(const float4*)(fcw + i);
        float4 b = *(const float4*)(fcw + i + 4);
        short8 v;
        __hip_bfloat16* h = (__hip_bfloat16*)&v;
        h[0] = __float2bfloat16(a.x); h[1] = __float2bfloat16(a.y);
        h[2] = __float2bfloat16(a.z); h[3] = __float2bfloat16(a.w);
        h[4] = __float2bfloat16(b.x); h[5] = __float2bfloat16(b.y);
        h[6] = __float2bfloat16(b.z); h[7] = __float2bfloat16(b.w);
        *(short8*)(fcw16 + i) = v;
    } else {
        int idx = (blk - CVT_BLKS) * 256 + threadIdx.x;   // 0..65535
        int o = idx & (D2 - 1);
        int i = idx >> 7;
        W2T[(size_t)i * D2 + o] =
            0.5f * (W[(size_t)(2 * o) * DIN + i] + W[(size_t)(2 * o + 1) * DIN + i]);
    }
}

// ---------------------------------------------------------------------------
// K2a: split-K GEMM for Z.  Zp[ks][b][q][o] = sum_{i in split} W2[o][i]*X[b][i][q]
// grid (BATCH, ZKS) = 1024 blocks -> 4 blocks/CU, W2T slices stay L2-hot.
// ---------------------------------------------------------------------------
__global__ __launch_bounds__(256) void k_z(const float* __restrict__ X,
                                           const float* __restrict__ W2T,
                                           float* __restrict__ Zp) {
    __shared__ float Xs[ZKL][NQ];   // 8 KB slice of X_b
    int b  = blockIdx.x;
    int ks = blockIdx.y;
    int t  = threadIdx.x;

    {
        const float4* src = (const float4*)(X + ((size_t)b * DIN + ks * ZKL) * NQ);
        float4* dst = (float4*)&Xs[0][0];
        for (int l = t; l < (ZKL * NQ) / 4; l += 256) dst[l] = src[l];
    }
    __syncthreads();

    int o  = t & (D2 - 1);
    int qh = (t >> 7) * 8;   // 0 or 8

    float acc[8] = {};
    #pragma unroll 4
    for (int i = 0; i < ZKL; ++i) {
        float w = W2T[(size_t)(ks * ZKL + i) * D2 + o];   // coalesced, L2-hot
        #pragma unroll
        for (int j = 0; j < 8; ++j) acc[j] = fmaf(w, Xs[i][qh + j], acc[j]);
    }

    float* zp = Zp + ((size_t)(ks * BATCH + b) * NQ) * D2;
    #pragma unroll
    for (int j = 0; j < 8; ++j)
        zp[(size_t)(qh + j) * D2 + o] = acc[j];          // coalesced per q
}

// ---------------------------------------------------------------------------
// Hand-unrolled Gauss-Jordan step: ALL register indices and shuffle lane
// expressions are compile-time constants (no scratch, rule #20 safe).
// Lane t<64: r = t&15 (row), cg = t>>4 (col group of 8), g[8] = tableau row.
// ---------------------------------------------------------------------------
#define GJ_STEP(K) do {                                                   \
    float piv = __shfl(g[(K) & 7], ((K) >> 3) * 16 + (K), 64);            \
    float fac = __shfl(g[(K) & 7], ((K) >> 3) * 16 + r, 64);              \
    float inv = 1.0f / piv;                                               \
    float f   = fac * inv;                                                \
    float p0 = __shfl(g[0], cg16 + (K), 64);                              \
    float p1 = __shfl(g[1], cg16 + (K), 64);                              \
    float p2 = __shfl(g[2], cg16 + (K), 64);                              \
    float p3 = __shfl(g[3], cg16 + (K), 64);                              \
    float p4 = __shfl(g[4], cg16 + (K), 64);                              \
    float p5 = __shfl(g[5], cg16 + (K), 64);                              \
    float p6 = __shfl(g[6], cg16 + (K), 64);                              \
    float p7 = __shfl(g[7], cg16 + (K), 64);                              \
    bool isk = (r == (K));                                                \
    g[0] = isk ? p0 * inv : fmaf(-f, p0, g[0]);                           \
    g[1] = isk ? p1 * inv : fmaf(-f, p1, g[1]);                           \
    g[2] = isk ? p2 * inv : fmaf(-f, p2, g[2]);                           \
    g[3] = isk ? p3 * inv : fmaf(-f, p3, g[3]);                           \
    g[4] = isk ? p4 * inv : fmaf(-f, p4, g[4]);                           \
    g[5] = isk ? p5 * inv : fmaf(-f, p5, g[5]);                           \
    g[6] = isk ? p6 * inv : fmaf(-f, p6, g[6]);                           \
    g[7] = isk ? p7 * inv : fmaf(-f, p7, g[7]);                           \
} while (0)

// ---------------------------------------------------------------------------
// K2b: per-batch epilogue, 512 threads (2 waves/SIMD).
// Z = sum Zp; G = Z^T Z; G^{-1} via single-wave register GJ (static unroll);
// E = Z G^{-1}; P2 = E Z^T -> bf16.  5 __syncthreads total.
// ---------------------------------------------------------------------------
__global__ __launch_bounds__(512) void k_gep(const float* __restrict__ Zp,
                                             __hip_bfloat16* __restrict__ P2) {
    __shared__ float Zt[NQ][ZPAD];    // Zt[q][o]
    __shared__ float Et[NQ][ZPAD];    // Et[q][o]
    __shared__ float Gi[NQ][36];      // [G | I] -> right half becomes G^{-1}

    int b = blockIdx.x;
    int t = threadIdx.x;

    // phase 1: reduce the ZKS partials (2048 floats = 512 float4, 1/thread)
    {
        const size_t s4 = (size_t)BATCH * NQ * D2 / 4;   // float4 per split
        const float4* zp = (const float4*)(Zp + ((size_t)b * NQ) * D2);
        float4 a0 = zp[t];
        float4 a1 = zp[t + s4];
        float4 a2 = zp[t + 2 * s4];
        float4 a3 = zp[t + 3 * s4];
        float4 s;
        s.x = (a0.x + a1.x) + (a2.x + a3.x);
        s.y = (a0.y + a1.y) + (a2.y + a3.y);
        s.z = (a0.z + a1.z) + (a2.z + a3.z);
        s.w = (a0.w + a1.w) + (a2.w + a3.w);
        int idx = t * 4;
        *(float4*)&Zt[idx >> 7][idx & (D2 - 1)] = s;
    }
    __syncthreads();

    // phase G: threads 0..255 compute G = Z^T Z, set up [G | I]
    if (t < 256) {
        int qq = t >> 4, rr = t & 15;
        float s = 0.f;
        for (int i = 0; i < D2; i += 4) {
            float4 a = *(const float4*)&Zt[qq][i];
            float4 c = *(const float4*)&Zt[rr][i];
            s = fmaf(a.x, c.x, s); s = fmaf(a.y, c.y, s);
            s = fmaf(a.z, c.z, s); s = fmaf(a.w, c.w, s);
        }
        Gi[qq][rr] = s;
        Gi[qq][NQ + rr] = (qq == rr) ? 1.f : 0.f;
    }
    __syncthreads();

    // phase GJ: wave 0 only, registers + shuffles, fully static.
    if (t < 64) {
        int r    = t & 15;
        int cg   = t >> 4;
        int cg16 = cg * 16;
        float g[8];
        #pragma unroll
        for (int j = 0; j < 8; ++j) g[j] = Gi[r][cg * 8 + j];
        GJ_STEP(0);  GJ_STEP(1);  GJ_STEP(2);  GJ_STEP(3);
        GJ_STEP(4);  GJ_STEP(5);  GJ_STEP(6);  GJ_STEP(7);
        GJ_STEP(8);  GJ_STEP(9);  GJ_STEP(10); GJ_STEP(11);
        GJ_STEP(12); GJ_STEP(13); GJ_STEP(14); GJ_STEP(15);
        if (cg >= 2) {   // write back G^{-1} (cols 16..31)
            #pragma unroll
            for (int j = 0; j < 8; ++j) Gi[r][cg * 8 + j] = g[j];
        }
    }
    __syncthreads();

    // phase E: E = Z G^{-1}, q-major. Thread -> (o, 4 q's).
    {
        int o  = t & (D2 - 1);
        int qg = (t >> 7) * 4;     // 0,4,8,12
        float acc[4] = {};
        #pragma unroll
        for (int rp = 0; rp < NQ; ++rp) {
            float z = Zt[rp][o];                       // contiguous b32
            #pragma unroll
            for (int j = 0; j < 4; ++j)
                acc[j] = fmaf(z, Gi[rp][NQ + qg + j], acc[j]);   // broadcast
        }
        #pragma unroll
        for (int j = 0; j < 4; ++j) Et[qg + j][o] = acc[j];
    }
    __syncthreads();

    // phase P2: P2 = E Z^T -> global bf16. Thread -> 4 rows, cols tj*8..+7
    {
        __hip_bfloat16* P2b = P2 + (size_t)b * KFC;
        int ti = t >> 4;          // 0..31
        int tj = t & 15;
        #pragma unroll
        for (int half = 0; half < 4; ++half) {
            int i = ti + half * 32;
            float acc[8] = {};
            #pragma unroll
            for (int r = 0; r < NQ; ++r) {
                float e   = Et[r][i];
                float4 z0 = *(const float4*)&Zt[r][tj * 8];
                float4 z1 = *(const float4*)&Zt[r][tj * 8 + 4];
                acc[0] = fmaf(e, z0.x, acc[0]); acc[1] = fmaf(e, z0.y, acc[1]);
                acc[2] = fmaf(e, z0.z, acc[2]); acc[3] = fmaf(e, z0.w, acc[3]);
                acc[4] = fmaf(e, z1.x, acc[4]); acc[5] = fmaf(e, z1.y, acc[5]);
                acc[6] = fmaf(e, z1.z, acc[6]); acc[7] = fmaf(e, z1.w, acc[7]);
            }
            short8 v;
            __hip_bfloat16* h = (__hip_bfloat16*)&v;
            #pragma unroll
            for (int j = 0; j < 8; ++j) h[j] = __float2bfloat16(acc[j]);
            *(short8*)(P2b + (size_t)i * D2 + tj * 8) = v;
        }
    }
}

// ---------------------------------------------------------------------------
// K3: MFMA split-K FC.  part[ks][b][c] = sum_{k in chunk} P2[b][k]*fcw[c][k]
// grid (16 bt, 32 ks) = 512 blocks -> 2 blocks/CU.
// ---------------------------------------------------------------------------
__global__ __launch_bounds__(256) void k_fc(const __hip_bfloat16* __restrict__ P2,
                                            const __hip_bfloat16* __restrict__ fcw16,
                                            float* __restrict__ part) {
    int bt = blockIdx.x;            // 0..15
    int ks = blockIdx.y;            // 0..31
    int t  = threadIdx.x;
    int lane = t & 63;
    int w    = t >> 6;
    int m  = lane & 15;
    int kg = (lane >> 4) * 8;

    const __hip_bfloat16* pa =
        P2 + (size_t)(bt * 16 + m) * KFC + ks * KCH + kg;

    int c0 = w * 32 + m;
    int c1 = c0 + 16;
    bool v0 = (c0 < NC), v1 = (c1 < NC);
    const __hip_bfloat16* pb0 =
        fcw16 + (size_t)(v0 ? c0 : 0) * KFC + ks * KCH + kg;
    const __hip_bfloat16* pb1 =
        fcw16 + (size_t)(v1 ? c1 : 0) * KFC + ks * KCH + kg;

    f32x4 acc0 = {0.f, 0.f, 0.f, 0.f};
    f32x4 acc1 = {0.f, 0.f, 0.f, 0.f};
    short8 zz = {};

    #pragma unroll 4
    for (int s = 0; s < STEPS; ++s) {
        short8 a  = *(const short8*)(pa + s * 32);
        short8 b0 = v0 ? *(const short8*)(pb0 + s * 32) : zz;
        short8 b1 = v1 ? *(const short8*)(pb1 + s * 32) : zz;
        acc0 = __builtin_amdgcn_mfma_f32_16x16x32_bf16(a, b0, acc0, 0, 0, 0);
        acc1 = __builtin_amdgcn_mfma_f32_16x16x32_bf16(a, b1, acc1, 0, 0, 0);
    }

    int r0 = (lane >> 4) * 4;
    float* pp = part + ((size_t)ks * BATCH + bt * 16 + r0) * D2;
    #pragma unroll
    for (int j = 0; j < 4; ++j) {
        pp[(size_t)j * D2 + w * 32 + m]      = acc0[j];
        pp[(size_t)j * D2 + w * 32 + 16 + m] = acc1[j];
    }
}

// ---------------------------------------------------------------------------
// K4: out[b][c] = fcb[c] + sum_ks part[ks][b][c]
// ---------------------------------------------------------------------------
__global__ __launch_bounds__(128) void k_red(const float* __restrict__ part,
                                             const float* __restrict__ fcb,
                                             float* __restrict__ out) {
    int b = blockIdx.x;
    int c = threadIdx.x;
    if (c < NC) {
        float s = fcb[c];
        #pragma unroll 8
        for (int ks = 0; ks < KS; ++ks)
            s += part[((size_t)ks * BATCH + b) * D2 + c];
        out[(size_t)b * NC + c] = s;
    }
}

extern "C" void kernel_launch(void* const* d_in, const int* in_sizes, int n_in,
                              void* d_out, int out_size, void* d_ws, size_t ws_size,
                              hipStream_t stream) {
    const float* X   = (const float*)d_in[0];   // (256, 512, 16)
    const float* W   = (const float*)d_in[1];   // (256, 512)
    const float* fcw = (const float*)d_in[2];   // (100, 16384)
    const float* fcb = (const float*)d_in[3];   // (100,)
    float* out = (float*)d_out;                 // (256, 100)

    float* ws = (float*)d_ws;
    float*          W2T   = ws;                                   // 65536 f
    float*          Zp    = ws + 65536;                           // 2097152 f (8 MB)
    float*          part  = Zp;                                   // aliased: Zp dead after k_gep
    __hip_bfloat16* P2b16 = (__hip_bfloat16*)(ws + 65536 + 2097152);            // 4194304 bf16
    __hip_bfloat16* fcw16 = (__hip_bfloat16*)(ws + 65536 + 2097152 + 2097152);  // 1638400 bf16
    // total ws ~= 19.4 MB

    k_prep<<<dim3(CVT_BLKS + 256), 256, 0, stream>>>(W, fcw, W2T, fcw16);
    k_z   <<<dim3(BATCH, ZKS), 256, 0, stream>>>(X, W2T, Zp);
    k_gep <<<dim3(BATCH), 512, 0, stream>>>(Zp, P2b16);
    k_fc  <<<dim3(16, KS), 256, 0, stream>>>(P2b16, fcw16, part);
    k_red <<<dim3(BATCH), 128, 0, stream>>>(part, fcb, out);
}